// Round 6
// baseline (391.427 us; speedup 1.0000x reference)
//
#include <hip/hip_runtime.h>
#include <hip/hip_bf16.h>

typedef short short8 __attribute__((ext_vector_type(8)));
typedef short short4v __attribute__((ext_vector_type(4)));
typedef float f32x4 __attribute__((ext_vector_type(4)));

#define S_LEN 2048
#define DIM   512
#define NBATCH 4

typedef unsigned short ushort_t;

__device__ __forceinline__ float b2f(unsigned short u) {
    union { unsigned u; float f; } x; x.u = ((unsigned)u) << 16; return x.f;
}
__device__ __forceinline__ unsigned short f2b(float f) {
    union { float f; unsigned u; } x; x.f = f;
    unsigned r = x.u + 0x7FFFu + ((x.u >> 16) & 1u);
    return (unsigned short)(r >> 16);
}
__device__ __forceinline__ float wave_sum(float v) {
    #pragma unroll
    for (int off = 32; off > 0; off >>= 1) v += __shfl_xor(v, off, 64);
    return v;
}

// ---------------------------------------------------------------------------
// K1: projections (MFMA). Inputs fp32, converted to bf16 during LDS staging
// (this exact staging+MFMA core was bit-identical to the VALU pipeline in
// R2/R3 cross-validation). z=0: Q=x@Wq^T+bq, z=1: K, z=2: V stored transposed
// per batch: Vt[b][d][s].
// ---------------------------------------------------------------------------
__global__ void proj_kernel(
    const float* __restrict__ x,
    const float* __restrict__ Wq, const float* __restrict__ bq,
    const float* __restrict__ Wk, const float* __restrict__ bk,
    const float* __restrict__ Wv, const float* __restrict__ bv,
    ushort_t* __restrict__ Q, ushort_t* __restrict__ Kp,
    ushort_t* __restrict__ Vt)
{
    __shared__ __align__(16) ushort_t As[128 * 40];
    __shared__ __align__(16) ushort_t Bs[128 * 40];
    const int z = blockIdx.z;
    const float* W    = (z == 0) ? Wq : (z == 1) ? Wk : Wv;
    const float* bias = (z == 0) ? bq : (z == 1) ? bk : bv;

    const int bm0 = blockIdx.x * 128, bn0 = blockIdx.y * 128;
    const int tid = threadIdx.x;
    const int lane = tid & 63, wave = tid >> 6;
    const int wm = wave >> 1, wn = wave & 1;
    const int ko = (lane >> 4) << 3;
    const int mrow = wm * 64 + (lane & 15);
    const int ncol = wn * 64 + (lane & 15);
    f32x4 acc[4][4] = {};

    for (int k0 = 0; k0 < DIM; k0 += 32) {
        __syncthreads();
        for (int v = tid; v < 128 * 8; v += 256) {
            int row = v >> 3, kc = (v & 7) << 2;
            f32x4 f = *(const f32x4*)&x[(size_t)(bm0 + row) * DIM + k0 + kc];
            short4v o;
            #pragma unroll
            for (int e = 0; e < 4; e++) o[e] = (short)f2b(f[e]);
            *(short4v*)&As[row * 40 + kc] = o;
        }
        for (int v = tid; v < 128 * 8; v += 256) {
            int row = v >> 3, kc = (v & 7) << 2;
            f32x4 f = *(const f32x4*)&W[(size_t)(bn0 + row) * DIM + k0 + kc];
            short4v o;
            #pragma unroll
            for (int e = 0; e < 4; e++) o[e] = (short)f2b(f[e]);
            *(short4v*)&Bs[row * 40 + kc] = o;
        }
        __syncthreads();

        short8 af[4], bf[4];
        #pragma unroll
        for (int i = 0; i < 4; i++)
            af[i] = *(const short8*)&As[(mrow + 16 * i) * 40 + ko];
        #pragma unroll
        for (int j = 0; j < 4; j++)
            bf[j] = *(const short8*)&Bs[(ncol + 16 * j) * 40 + ko];
        #pragma unroll
        for (int i = 0; i < 4; i++)
            #pragma unroll
            for (int j = 0; j < 4; j++)
                acc[i][j] = __builtin_amdgcn_mfma_f32_16x16x32_bf16(
                    af[i], bf[j], acc[i][j], 0, 0, 0);
    }

    const int quad = lane >> 4;
    #pragma unroll
    for (int j = 0; j < 4; j++) {
        int gcol = bn0 + wn * 64 + 16 * j + (lane & 15);
        float bb = bias[gcol];
        #pragma unroll
        for (int i = 0; i < 4; i++)
            #pragma unroll
            for (int r = 0; r < 4; r++) {
                int grow = bm0 + wm * 64 + 16 * i + quad * 4 + r;
                ushort_t o = f2b(acc[i][j][r] + bb);
                if (z == 0)      Q[(size_t)grow * DIM + gcol] = o;
                else if (z == 1) Kp[(size_t)grow * DIM + gcol] = o;
                else {
                    int bb2 = grow >> 11, s = grow & 2047;
                    Vt[((size_t)bb2 * DIM + gcol) * S_LEN + s] = o;
                }
            }
    }
}

// K2: row norms |q_s|^2, |k_t|^2 from bf16 Q/K (self-consistent with MFMA).
__global__ void norms_kernel(const ushort_t* __restrict__ Q,
                             const ushort_t* __restrict__ Kp,
                             float* __restrict__ nq, float* __restrict__ nk)
{
    const int wave = threadIdx.x >> 6, lane = threadIdx.x & 63;
    const int row = blockIdx.x * 4 + wave;  // 0..8191
    const ushort_t* src = (blockIdx.y == 0) ? Q : Kp;
    float* dst = (blockIdx.y == 0) ? nq : nk;
    short8 v = *(const short8*)&src[(size_t)row * DIM + lane * 8];
    float s = 0.f;
    #pragma unroll
    for (int e = 0; e < 8; e++) { float f = b2f((ushort_t)v[e]); s += f * f; }
    s = wave_sum(s);
    if (lane == 0) dst[row] = s;
}

// K3: attn[s,t] = exp(-max(|q|^2+|k|^2-2 q.k, eps)/512), fp32, into the probs
// region of d_out (scratch until normalized in place).
__global__ void score_kernel(const ushort_t* __restrict__ Q,
                             const ushort_t* __restrict__ Kp,
                             const float* __restrict__ nq,
                             const float* __restrict__ nk,
                             float* __restrict__ attn)
{
    __shared__ __align__(16) ushort_t As[128 * 40];
    __shared__ __align__(16) ushort_t Bs[128 * 40];
    const int b = blockIdx.z;
    const ushort_t* A  = Q  + (size_t)b * S_LEN * DIM;
    const ushort_t* Bt = Kp + (size_t)b * S_LEN * DIM;
    const int bm0 = blockIdx.x * 128, bn0 = blockIdx.y * 128;
    const int tid = threadIdx.x;
    const int lane = tid & 63, wave = tid >> 6;
    const int wm = wave >> 1, wn = wave & 1;
    const int ko = (lane >> 4) << 3;
    const int mrow = wm * 64 + (lane & 15);
    const int ncol = wn * 64 + (lane & 15);
    f32x4 acc[4][4] = {};

    for (int k0 = 0; k0 < DIM; k0 += 32) {
        __syncthreads();
        for (int v = tid; v < 128 * 4; v += 256) {
            int row = v >> 2, kc = (v & 3) << 3;
            *(short8*)&As[row * 40 + kc] =
                *(const short8*)&A[(size_t)(bm0 + row) * DIM + k0 + kc];
        }
        for (int v = tid; v < 128 * 4; v += 256) {
            int row = v >> 2, kc = (v & 3) << 3;
            *(short8*)&Bs[row * 40 + kc] =
                *(const short8*)&Bt[(size_t)(bn0 + row) * DIM + k0 + kc];
        }
        __syncthreads();

        short8 af[4], bf[4];
        #pragma unroll
        for (int i = 0; i < 4; i++)
            af[i] = *(const short8*)&As[(mrow + 16 * i) * 40 + ko];
        #pragma unroll
        for (int j = 0; j < 4; j++)
            bf[j] = *(const short8*)&Bs[(ncol + 16 * j) * 40 + ko];
        #pragma unroll
        for (int i = 0; i < 4; i++)
            #pragma unroll
            for (int j = 0; j < 4; j++)
                acc[i][j] = __builtin_amdgcn_mfma_f32_16x16x32_bf16(
                    af[i], bf[j], acc[i][j], 0, 0, 0);
    }

    float* out = attn + (size_t)b * S_LEN * S_LEN;
    const int quad = lane >> 4;

    float nqv[16], nkv[4];
    #pragma unroll
    for (int i = 0; i < 4; i++)
        #pragma unroll
        for (int r = 0; r < 4; r++)
            nqv[i * 4 + r] = nq[b * S_LEN + bm0 + wm * 64 + 16 * i + quad * 4 + r];
    #pragma unroll
    for (int j = 0; j < 4; j++)
        nkv[j] = nk[b * S_LEN + bn0 + wn * 64 + 16 * j + (lane & 15)];

    #pragma unroll
    for (int i = 0; i < 4; i++)
        #pragma unroll
        for (int j = 0; j < 4; j++)
            #pragma unroll
            for (int r = 0; r < 4; r++) {
                int grow = bm0 + wm * 64 + 16 * i + quad * 4 + r;
                int gcol = bn0 + wn * 64 + 16 * j + (lane & 15);
                float sq = nqv[i * 4 + r] + nkv[j] - 2.0f * acc[i][j][r];
                sq = fmaxf(sq, 1e-12f);
                out[(size_t)grow * S_LEN + gcol] = __expf(sq * (-1.0f / 512.0f));
            }
}

// K4a: column sums N_C[t] = sum_s attn[s,t] (atomics, NC pre-zeroed)
__global__ void colsum_kernel(const float* __restrict__ attn,
                              float* __restrict__ NC)
{
    const int b = blockIdx.z;
    const int t = blockIdx.x * 256 + threadIdx.x;
    const int s0 = blockIdx.y * 128;
    const float* base = attn + ((size_t)b * S_LEN + s0) * S_LEN + t;
    float a0 = 0.f, a1 = 0.f, a2 = 0.f, a3 = 0.f;
    for (int i = 0; i < 128; i += 4) {
        a0 += base[(size_t)(i + 0) * S_LEN];
        a1 += base[(size_t)(i + 1) * S_LEN];
        a2 += base[(size_t)(i + 2) * S_LEN];
        a3 += base[(size_t)(i + 3) * S_LEN];
    }
    atomicAdd(&NC[b * S_LEN + t], (a0 + a1) + (a2 + a3));
}

// K4b: c = N_C^(-1/2)
__global__ void finalize_c_kernel(const float* __restrict__ NC, float* __restrict__ c)
{
    int i = blockIdx.x * 256 + threadIdx.x;
    c[i] = 1.0f / sqrtf(NC[i]);
}

// K4c: r[s] = 1 / sum_t attn[s,t]*c[t]   (N_R cancels in the p=1 normalize)
__global__ void rowsum_kernel(const float* __restrict__ attn,
                              const float* __restrict__ c, float* __restrict__ r)
{
    const int wave = threadIdx.x >> 6, lane = threadIdx.x & 63;
    const int R = blockIdx.x * 4 + wave;  // 0..8191
    const int b = R >> 11;
    const float* row = attn + (size_t)R * S_LEN;
    const float* cb = c + (b << 11);
    float acc = 0.f;
    #pragma unroll
    for (int it = 0; it < 8; it++) {
        int t = it * 256 + lane * 4;
        f32x4 a = *(const f32x4*)&row[t];
        f32x4 cv = *(const f32x4*)&cb[t];
        #pragma unroll
        for (int e = 0; e < 4; e++) acc = fmaf(a[e], cv[e], acc);
    }
    acc = wave_sum(acc);
    if (lane == 0) r[R] = 1.0f / acc;
}

// K4d: probs = attn * c[t] * r[s], in place (fp32; attn region IS the output)
__global__ void probs_kernel(float* __restrict__ attn,
                             const float* __restrict__ c,
                             const float* __restrict__ r)
{
    const int s = blockIdx.x, b = blockIdx.y;
    float* row = attn + ((size_t)b * S_LEN + s) * S_LEN;
    const float* cb = c + (b << 11);
    const float rs = r[b * S_LEN + s];
    const int t = threadIdx.x * 8;
    f32x4 a0 = *(const f32x4*)&row[t];
    f32x4 a1 = *(const f32x4*)&row[t + 4];
    f32x4 c0 = *(const f32x4*)&cb[t];
    f32x4 c1 = *(const f32x4*)&cb[t + 4];
    #pragma unroll
    for (int e = 0; e < 4; e++) { a0[e] = a0[e] * c0[e] * rs; a1[e] = a1[e] * c1[e] * rs; }
    *(f32x4*)&row[t] = a0;
    *(f32x4*)&row[t + 4] = a1;
}

// ---------------------------------------------------------------------------
// K5: out = probs @ V (MFMA). A = probs fp32 (converted to bf16 in staging),
// B = Vt bf16 (contiguous along k=t). fp32 stores to out.
// ---------------------------------------------------------------------------
__global__ void out_gemm_kernel(const float* __restrict__ probs,
                                const ushort_t* __restrict__ Vt,
                                float* __restrict__ outp)
{
    __shared__ __align__(16) ushort_t As[128 * 40];
    __shared__ __align__(16) ushort_t Bs[64 * 40];
    const int b = blockIdx.z;
    const float* A = probs + (size_t)b * S_LEN * S_LEN;
    const ushort_t* Bt = Vt + (size_t)b * DIM * S_LEN;
    const int bm0 = blockIdx.x * 128, bn0 = blockIdx.y * 64;
    const int tid = threadIdx.x;
    const int lane = tid & 63, wave = tid >> 6;
    const int wm = wave >> 1, wn = wave & 1;
    const int ko = (lane >> 4) << 3;
    const int mrow = wm * 64 + (lane & 15);
    const int ncol = wn * 32 + (lane & 15);
    f32x4 acc[4][2] = {};

    for (int k0 = 0; k0 < S_LEN; k0 += 32) {
        __syncthreads();
        for (int v = tid; v < 128 * 8; v += 256) {
            int row = v >> 3, kc = (v & 7) << 2;
            f32x4 f = *(const f32x4*)&A[(size_t)(bm0 + row) * S_LEN + k0 + kc];
            short4v o;
            #pragma unroll
            for (int e = 0; e < 4; e++) o[e] = (short)f2b(f[e]);
            *(short4v*)&As[row * 40 + kc] = o;
        }
        for (int v = tid; v < 64 * 4; v += 256) {
            int row = v >> 2, kc = (v & 3) << 3;
            *(short8*)&Bs[row * 40 + kc] =
                *(const short8*)&Bt[(size_t)(bn0 + row) * S_LEN + k0 + kc];
        }
        __syncthreads();

        short8 af[4], bf[2];
        #pragma unroll
        for (int i = 0; i < 4; i++)
            af[i] = *(const short8*)&As[(mrow + 16 * i) * 40 + ko];
        #pragma unroll
        for (int j = 0; j < 2; j++)
            bf[j] = *(const short8*)&Bs[(ncol + 16 * j) * 40 + ko];
        #pragma unroll
        for (int i = 0; i < 4; i++)
            #pragma unroll
            for (int j = 0; j < 2; j++)
                acc[i][j] = __builtin_amdgcn_mfma_f32_16x16x32_bf16(
                    af[i], bf[j], acc[i][j], 0, 0, 0);
    }

    float* C = outp + (size_t)b * S_LEN * DIM;
    const int quad = lane >> 4;
    #pragma unroll
    for (int i = 0; i < 4; i++)
        #pragma unroll
        for (int j = 0; j < 2; j++)
            #pragma unroll
            for (int r = 0; r < 4; r++) {
                int grow = bm0 + wm * 64 + 16 * i + quad * 4 + r;
                int gcol = bn0 + wn * 32 + 16 * j + (lane & 15);
                C[(size_t)grow * DIM + gcol] = acc[i][j][r];
            }
}

extern "C" void kernel_launch(void* const* d_in, const int* in_sizes, int n_in,
                              void* d_out, int out_size, void* d_ws, size_t ws_size,
                              hipStream_t stream)
{
    const float* x  = (const float*)d_in[0];
    const float* Wq = (const float*)d_in[1];
    const float* bq = (const float*)d_in[2];
    const float* Wk = (const float*)d_in[3];
    const float* bk = (const float*)d_in[4];
    const float* Wv = (const float*)d_in[5];
    const float* bv = (const float*)d_in[6];

    // FP32 outputs (reference output dtype is float32).
    float* out   = (float*)d_out;                          // [4][2048][512]
    float* probs = out + (size_t)NBATCH * S_LEN * DIM;     // [4][2048][2048]

    // Q,K bf16 parked in the out region (16.8 MB = exactly 2x 8.4 MB); dead
    // before out_gemm overwrites it. Vt bf16 + small floats in ws (8.6 MB).
    ushort_t* Qb = (ushort_t*)d_out;                   // [8192][512] bf16
    ushort_t* Kb = Qb + (size_t)8192 * DIM;            // [8192][512] bf16
    ushort_t* Vt = (ushort_t*)d_ws;                    // [4][512][2048] bf16
    float* nq = (float*)(Vt + (size_t)NBATCH * DIM * S_LEN);  // [8192]
    float* nk = nq + 8192;                             // [8192]
    float* NC = nk + 8192;                             // [8192]
    float* cc = NC + 8192;                             // [8192]
    float* rr = cc + 8192;                             // [8192]

    hipMemsetAsync(NC, 0, 8192 * sizeof(float), stream);

    proj_kernel<<<dim3(64, 4, 3), 256, 0, stream>>>(x, Wq, bq, Wk, bk, Wv, bv,
                                                    Qb, Kb, Vt);
    norms_kernel<<<dim3(2048, 2), 256, 0, stream>>>(Qb, Kb, nq, nk);
    score_kernel<<<dim3(16, 16, NBATCH), 256, 0, stream>>>(Qb, Kb, nq, nk, probs);
    colsum_kernel<<<dim3(8, 16, NBATCH), 256, 0, stream>>>(probs, NC);
    finalize_c_kernel<<<32, 256, 0, stream>>>(NC, cc);
    rowsum_kernel<<<2048, 256, 0, stream>>>(probs, cc, rr);
    probs_kernel<<<dim3(S_LEN, NBATCH), 256, 0, stream>>>(probs, cc, rr);
    out_gemm_kernel<<<dim3(16, 8, NBATCH), 256, 0, stream>>>(probs, Vt, out);
}

// Round 7
// 248.448 us; speedup vs baseline: 1.5755x; 1.5755x over previous
//
#include <hip/hip_runtime.h>
#include <hip/hip_bf16.h>

typedef short short8 __attribute__((ext_vector_type(8)));
typedef short short4v __attribute__((ext_vector_type(4)));
typedef float f32x4 __attribute__((ext_vector_type(4)));

#define S_LEN 2048
#define DIM   512
#define NBATCH 4

typedef unsigned short ushort_t;

__device__ __forceinline__ float b2f(unsigned short u) {
    union { unsigned u; float f; } x; x.u = ((unsigned)u) << 16; return x.f;
}
__device__ __forceinline__ unsigned short f2b(float f) {
    union { float f; unsigned u; } x; x.f = f;
    unsigned r = x.u + 0x7FFFu + ((x.u >> 16) & 1u);
    return (unsigned short)(r >> 16);
}
__device__ __forceinline__ float wave_sum(float v) {
    #pragma unroll
    for (int off = 32; off > 0; off >>= 1) v += __shfl_xor(v, off, 64);
    return v;
}
// Async global->LDS, 16B per lane; LDS dest = wave-uniform base + lane*16.
__device__ __forceinline__ void gld16(const void* g, void* l) {
    __builtin_amdgcn_global_load_lds(
        (const __attribute__((address_space(1))) unsigned int*)g,
        (__attribute__((address_space(3))) unsigned int*)l, 16, 0, 0);
}

// ---------------------------------------------------------------------------
// K1: projections (MFMA, fp32 inputs converted in staging) — unchanged from
// the passing round 6. z=0: Q, z=1: K, z=2: V stored transposed Vt[b][d][s].
// ---------------------------------------------------------------------------
__global__ void proj_kernel(
    const float* __restrict__ x,
    const float* __restrict__ Wq, const float* __restrict__ bq,
    const float* __restrict__ Wk, const float* __restrict__ bk,
    const float* __restrict__ Wv, const float* __restrict__ bv,
    ushort_t* __restrict__ Q, ushort_t* __restrict__ Kp,
    ushort_t* __restrict__ Vt)
{
    __shared__ __align__(16) ushort_t As[128 * 40];
    __shared__ __align__(16) ushort_t Bs[128 * 40];
    const int z = blockIdx.z;
    const float* W    = (z == 0) ? Wq : (z == 1) ? Wk : Wv;
    const float* bias = (z == 0) ? bq : (z == 1) ? bk : bv;

    const int bm0 = blockIdx.x * 128, bn0 = blockIdx.y * 128;
    const int tid = threadIdx.x;
    const int lane = tid & 63, wave = tid >> 6;
    const int wm = wave >> 1, wn = wave & 1;
    const int ko = (lane >> 4) << 3;
    const int mrow = wm * 64 + (lane & 15);
    const int ncol = wn * 64 + (lane & 15);
    f32x4 acc[4][4] = {};

    for (int k0 = 0; k0 < DIM; k0 += 32) {
        __syncthreads();
        for (int v = tid; v < 128 * 8; v += 256) {
            int row = v >> 3, kc = (v & 7) << 2;
            f32x4 f = *(const f32x4*)&x[(size_t)(bm0 + row) * DIM + k0 + kc];
            short4v o;
            #pragma unroll
            for (int e = 0; e < 4; e++) o[e] = (short)f2b(f[e]);
            *(short4v*)&As[row * 40 + kc] = o;
        }
        for (int v = tid; v < 128 * 8; v += 256) {
            int row = v >> 3, kc = (v & 7) << 2;
            f32x4 f = *(const f32x4*)&W[(size_t)(bn0 + row) * DIM + k0 + kc];
            short4v o;
            #pragma unroll
            for (int e = 0; e < 4; e++) o[e] = (short)f2b(f[e]);
            *(short4v*)&Bs[row * 40 + kc] = o;
        }
        __syncthreads();

        short8 af[4], bf[4];
        #pragma unroll
        for (int i = 0; i < 4; i++)
            af[i] = *(const short8*)&As[(mrow + 16 * i) * 40 + ko];
        #pragma unroll
        for (int j = 0; j < 4; j++)
            bf[j] = *(const short8*)&Bs[(ncol + 16 * j) * 40 + ko];
        #pragma unroll
        for (int i = 0; i < 4; i++)
            #pragma unroll
            for (int j = 0; j < 4; j++)
                acc[i][j] = __builtin_amdgcn_mfma_f32_16x16x32_bf16(
                    af[i], bf[j], acc[i][j], 0, 0, 0);
    }

    const int quad = lane >> 4;
    #pragma unroll
    for (int j = 0; j < 4; j++) {
        int gcol = bn0 + wn * 64 + 16 * j + (lane & 15);
        float bb = bias[gcol];
        #pragma unroll
        for (int i = 0; i < 4; i++)
            #pragma unroll
            for (int r = 0; r < 4; r++) {
                int grow = bm0 + wm * 64 + 16 * i + quad * 4 + r;
                ushort_t o = f2b(acc[i][j][r] + bb);
                if (z == 0)      Q[(size_t)grow * DIM + gcol] = o;
                else if (z == 1) Kp[(size_t)grow * DIM + gcol] = o;
                else {
                    int bb2 = grow >> 11, s = grow & 2047;
                    Vt[((size_t)bb2 * DIM + gcol) * S_LEN + s] = o;
                }
            }
    }
}

// K2: row norms |q_s|^2, |k_t|^2 (unchanged).
__global__ void norms_kernel(const ushort_t* __restrict__ Q,
                             const ushort_t* __restrict__ Kp,
                             float* __restrict__ nq, float* __restrict__ nk)
{
    const int wave = threadIdx.x >> 6, lane = threadIdx.x & 63;
    const int row = blockIdx.x * 4 + wave;  // 0..8191
    const ushort_t* src = (blockIdx.y == 0) ? Q : Kp;
    float* dst = (blockIdx.y == 0) ? nq : nk;
    short8 v = *(const short8*)&src[(size_t)row * DIM + lane * 8];
    float s = 0.f;
    #pragma unroll
    for (int e = 0; e < 8; e++) { float f = b2f((ushort_t)v[e]); s += f * f; }
    s = wave_sum(s);
    if (lane == 0) dst[row] = s;
}

// ---------------------------------------------------------------------------
// K3: score. attnb[s,t] = bf16(exp(-max(|q|^2+|k|^2-2qk, eps)/512)) -> ws,
// with fused column-sum atomics into NC. Staging via global_load_lds with
// chunk swizzle c4 ^= (row>>1)&3 (conflict-free b128 frag reads).
// LDS layout: tile [128][32] bf16, 16B-chunk f holds (row=f>>2, c4 swizzled).
// ---------------------------------------------------------------------------
__global__ void score_kernel(const ushort_t* __restrict__ Q,
                             const ushort_t* __restrict__ Kp,
                             const float* __restrict__ nq,
                             const float* __restrict__ nk,
                             ushort_t* __restrict__ attnb,
                             float* __restrict__ NC)
{
    __shared__ __align__(16) ushort_t As[128 * 32];
    __shared__ __align__(16) ushort_t Bs[128 * 32];
    const int b = blockIdx.z;
    const ushort_t* A  = Q  + (size_t)b * S_LEN * DIM;
    const ushort_t* Bt = Kp + (size_t)b * S_LEN * DIM;
    const int bm0 = blockIdx.x * 128, bn0 = blockIdx.y * 128;
    const int tid = threadIdx.x;
    const int lane = tid & 63, wave = tid >> 6;
    const int wm = wave >> 1, wn = wave & 1;
    const int quad = lane >> 4;
    const int mrow = wm * 64 + (lane & 15);
    const int ncol = wn * 64 + (lane & 15);
    f32x4 acc[4][4] = {};

    for (int k0 = 0; k0 < DIM; k0 += 32) {
        __syncthreads();
        #pragma unroll
        for (int u = 0; u < 2; u++) {
            int f = u * 256 + tid;
            int row = f >> 2, c4 = (f & 3) ^ ((row >> 1) & 3);
            gld16(&A[(size_t)(bm0 + row) * DIM + k0 + c4 * 8],
                  &As[(u * 256 + wave * 64) * 8]);
        }
        #pragma unroll
        for (int u = 0; u < 2; u++) {
            int f = u * 256 + tid;
            int row = f >> 2, c4 = (f & 3) ^ ((row >> 1) & 3);
            gld16(&Bt[(size_t)(bn0 + row) * DIM + k0 + c4 * 8],
                  &Bs[(u * 256 + wave * 64) * 8]);
        }
        __syncthreads();

        short8 af[4], bf[4];
        #pragma unroll
        for (int i = 0; i < 4; i++) {
            int row = mrow + 16 * i;
            af[i] = *(const short8*)&As[row * 32 + (quad ^ ((row >> 1) & 3)) * 8];
        }
        #pragma unroll
        for (int j = 0; j < 4; j++) {
            int row = ncol + 16 * j;
            bf[j] = *(const short8*)&Bs[row * 32 + (quad ^ ((row >> 1) & 3)) * 8];
        }
        #pragma unroll
        for (int i = 0; i < 4; i++)
            #pragma unroll
            for (int j = 0; j < 4; j++)
                acc[i][j] = __builtin_amdgcn_mfma_f32_16x16x32_bf16(
                    af[i], bf[j], acc[i][j], 0, 0, 0);
    }

    ushort_t* ob = attnb + (size_t)b * S_LEN * S_LEN;
    float nqv[16], nkv[4];
    #pragma unroll
    for (int i = 0; i < 4; i++)
        #pragma unroll
        for (int r = 0; r < 4; r++)
            nqv[i * 4 + r] = nq[b * S_LEN + bm0 + wm * 64 + 16 * i + quad * 4 + r];
    #pragma unroll
    for (int j = 0; j < 4; j++)
        nkv[j] = nk[b * S_LEN + bn0 + wn * 64 + 16 * j + (lane & 15)];

    float cp[4] = {0.f, 0.f, 0.f, 0.f};
    #pragma unroll
    for (int i = 0; i < 4; i++)
        #pragma unroll
        for (int j = 0; j < 4; j++)
            #pragma unroll
            for (int r = 0; r < 4; r++) {
                int grow = bm0 + wm * 64 + 16 * i + quad * 4 + r;
                int gcol = bn0 + wn * 64 + 16 * j + (lane & 15);
                float sq = nqv[i * 4 + r] + nkv[j] - 2.0f * acc[i][j][r];
                sq = fmaxf(sq, 1e-12f);
                ushort_t ub = f2b(__expf(sq * (-1.0f / 512.0f)));
                ob[(size_t)grow * S_LEN + gcol] = ub;
                cp[j] += b2f(ub);  // bf16-consistent column partial
            }
    // reduce over quads (lanes ^16, ^32) then one atomic per (wave, lane<16, j)
    #pragma unroll
    for (int j = 0; j < 4; j++) {
        float v = cp[j];
        v += __shfl_xor(v, 16, 64);
        v += __shfl_xor(v, 32, 64);
        if (quad == 0) {
            int gcol = bn0 + wn * 64 + 16 * j + (lane & 15);
            atomicAdd(&NC[b * S_LEN + gcol], v);
        }
    }
}

// K4a: c = N_C^(-1/2)
__global__ void finalize_c_kernel(const float* __restrict__ NC, float* __restrict__ c)
{
    int i = blockIdx.x * 256 + threadIdx.x;
    c[i] = 1.0f / sqrtf(NC[i]);
}

// K4b: Vt[b][d][s] *= c[b*S+s] in place (folds the column factor into V)
__global__ void scale_vt_kernel(ushort_t* __restrict__ Vt,
                                const float* __restrict__ cc)
{
    size_t idx = ((size_t)blockIdx.x * 256 + threadIdx.x) * 8;
    int s0 = (int)(idx & 2047);
    int b  = (int)(idx >> 20);                // 512*2048 elems per batch
    const float* cb = cc + (b << 11);
    short8 v = *(short8*)&Vt[idx];
    #pragma unroll
    for (int e = 0; e < 8; e++)
        v[e] = (short)f2b(b2f((ushort_t)v[e]) * cb[s0 + e]);
    *(short8*)&Vt[idx] = v;
}

// K5: fused rowsum + probs write. One block per row: read bf16 attn row,
// r = 1/sum(attn*c), write fp32 probs = attn*c*r, save r for out epilogue.
__global__ void rowsumprobs_kernel(const ushort_t* __restrict__ attnb,
                                   const float* __restrict__ cc,
                                   float* __restrict__ probs,
                                   float* __restrict__ rr)
{
    __shared__ float red[4];
    const int s = blockIdx.x, b = blockIdx.y;
    const size_t R = (size_t)b * S_LEN + s;
    const ushort_t* row = attnb + R * S_LEN;
    const float* cb = cc + (b << 11);
    const int t = threadIdx.x * 8;
    const int wave = threadIdx.x >> 6, lane = threadIdx.x & 63;

    short8 av = *(const short8*)&row[t];
    float pv[8], acc = 0.f;
    #pragma unroll
    for (int e = 0; e < 8; e++) { pv[e] = b2f((ushort_t)av[e]) * cb[t + e]; acc += pv[e]; }
    acc = wave_sum(acc);
    if (lane == 0) red[wave] = acc;
    __syncthreads();
    float rs = 1.0f / (red[0] + red[1] + red[2] + red[3]);

    float* prow = probs + R * S_LEN;
    f32x4 o0, o1;
    #pragma unroll
    for (int e = 0; e < 4; e++) { o0[e] = pv[e] * rs; o1[e] = pv[4 + e] * rs; }
    *(f32x4*)&prow[t] = o0;
    *(f32x4*)&prow[t + 4] = o1;
    if (threadIdx.x == 0) rr[R] = rs;
}

// ---------------------------------------------------------------------------
// K6: out = r ⊙ (attnb · Vtc). Pure bf16 GEMM, global_load_lds staging,
// 512 threads (8 waves, 2x4), BM=128 BN=64 BK=32, fp32 out.
// ---------------------------------------------------------------------------
__global__ void out_gemm_kernel(const ushort_t* __restrict__ attnb,
                                const ushort_t* __restrict__ Vtc,
                                const float* __restrict__ rr,
                                float* __restrict__ outp)
{
    __shared__ __align__(16) ushort_t As[128 * 32];
    __shared__ __align__(16) ushort_t Bs[64 * 32];
    const int b = blockIdx.z;
    const ushort_t* A  = attnb + (size_t)b * S_LEN * S_LEN;
    const ushort_t* Bt = Vtc + (size_t)b * DIM * S_LEN;
    const int bm0 = blockIdx.x * 128, bn0 = blockIdx.y * 64;
    const int tid = threadIdx.x;
    const int lane = tid & 63, wave = tid >> 6;
    const int wm = wave >> 2, wn = wave & 3;
    const int quad = lane >> 4;
    const int mrow = wm * 64 + (lane & 15);
    const int ncol = wn * 16 + (lane & 15);
    f32x4 acc[4] = {};

    for (int k0 = 0; k0 < S_LEN; k0 += 32) {
        __syncthreads();
        {   // A: 512 chunks, one per thread
            int f = tid;
            int row = f >> 2, c4 = (f & 3) ^ ((row >> 1) & 3);
            gld16(&A[(size_t)(bm0 + row) * S_LEN + k0 + c4 * 8],
                  &As[(wave * 64) * 8]);
        }
        if (wave < 4) {  // B: 256 chunks, waves 0..3
            int f = wave * 64 + lane;
            int row = f >> 2, c4 = (f & 3) ^ ((row >> 1) & 3);
            gld16(&Bt[(size_t)(bn0 + row) * S_LEN + k0 + c4 * 8],
                  &Bs[(wave * 64) * 8]);
        }
        __syncthreads();

        short8 af[4], bf;
        #pragma unroll
        for (int i = 0; i < 4; i++) {
            int row = mrow + 16 * i;
            af[i] = *(const short8*)&As[row * 32 + (quad ^ ((row >> 1) & 3)) * 8];
        }
        {
            int row = ncol;
            bf = *(const short8*)&Bs[row * 32 + (quad ^ ((row >> 1) & 3)) * 8];
        }
        #pragma unroll
        for (int i = 0; i < 4; i++)
            acc[i] = __builtin_amdgcn_mfma_f32_16x16x32_bf16(af[i], bf, acc[i], 0, 0, 0);
    }

    float* C = outp + (size_t)b * S_LEN * DIM;
    const int gcol = bn0 + ncol - wn * 16 + wn * 16;  // = bn0 + wn*16 + (lane&15)
    #pragma unroll
    for (int i = 0; i < 4; i++)
        #pragma unroll
        for (int r = 0; r < 4; r++) {
            int grow = bm0 + wm * 64 + 16 * i + quad * 4 + r;
            float rs = rr[b * S_LEN + grow];
            C[(size_t)grow * DIM + gcol] = acc[i][r] * rs;
        }
}

extern "C" void kernel_launch(void* const* d_in, const int* in_sizes, int n_in,
                              void* d_out, int out_size, void* d_ws, size_t ws_size,
                              hipStream_t stream)
{
    const float* x  = (const float*)d_in[0];
    const float* Wq = (const float*)d_in[1];
    const float* bq = (const float*)d_in[2];
    const float* Wk = (const float*)d_in[3];
    const float* bk = (const float*)d_in[4];
    const float* Wv = (const float*)d_in[5];
    const float* bv = (const float*)d_in[6];

    float* out   = (float*)d_out;                          // [4][2048][512] fp32
    float* probs = out + (size_t)NBATCH * S_LEN * DIM;     // [4][2048][2048] fp32

    // Q,K bf16 parked in the out region (dead before out_gemm writes it).
    ushort_t* Qb = (ushort_t*)d_out;                   // [8192][512] bf16
    ushort_t* Kb = Qb + (size_t)8192 * DIM;            // [8192][512] bf16
    // ws: Vt 8.4MB | attnb 16.8MB | small floats  (total ~25.4 MB)
    ushort_t* Vt    = (ushort_t*)d_ws;                 // [4][512][2048] bf16
    ushort_t* attnb = Vt + (size_t)NBATCH * DIM * S_LEN;  // [4][2048][2048] bf16
    float* nq = (float*)(attnb + (size_t)NBATCH * S_LEN * S_LEN);
    float* nk = nq + 8192;
    float* NC = nk + 8192;
    float* cc = NC + 8192;
    float* rr = cc + 8192;

    hipMemsetAsync(NC, 0, 8192 * sizeof(float), stream);

    proj_kernel<<<dim3(64, 4, 3), 256, 0, stream>>>(x, Wq, bq, Wk, bk, Wv, bv,
                                                    Qb, Kb, Vt);
    norms_kernel<<<dim3(2048, 2), 256, 0, stream>>>(Qb, Kb, nq, nk);
    score_kernel<<<dim3(16, 16, NBATCH), 256, 0, stream>>>(Qb, Kb, nq, nk,
                                                           attnb, NC);
    finalize_c_kernel<<<32, 256, 0, stream>>>(NC, cc);
    scale_vt_kernel<<<2048, 256, 0, stream>>>(Vt, cc);
    rowsumprobs_kernel<<<dim3(S_LEN, NBATCH), 256, 0, stream>>>(attnb, cc,
                                                                probs, rr);
    out_gemm_kernel<<<dim3(16, 8, NBATCH), 512, 0, stream>>>(attnb, Vt, rr, out);
}